// Round 5
// baseline (255.554 us; speedup 1.0000x reference)
//
#include <hip/hip_runtime.h>
#include <hip/hip_bf16.h>

// Problem constants
#define B_    32
#define C_    256     // Cin == Cout
#define H_    56
#define W_    56
#define HP    58      // padded H
#define WPAD  58      // padded W
#define HW    3136    // H_*W_
#define CHW   802816  // C_*H_*W_
#define M_TOT 100352  // B_*H_*W_

typedef char  charx16 __attribute__((ext_vector_type(16)));
typedef int   intx4   __attribute__((ext_vector_type(4)));

#define XPAD_BYTES (B_ * HP * WPAD * C_)        // 27,557,888 (i8)
#define WPK_BYTES  (C_ * 9 * C_)                // 589,824 (i8)

__device__ __forceinline__ int sgn8(float f) {
  return ((f > 0.f) ? 1 : ((f < 0.f) ? -1 : 0)) & 0xff;
}

// ---------------------------------------------------------------------------
// Pack weights: wq[co][s][ci] i8 = sign(w1)+sign(w2) in {-2..2} (= 2*w_ter),
// alphah[co] = 0.5*(mean|w1|+mean|w2|). Coalesced loads via LDS stage.
// ---------------------------------------------------------------------------
__global__ __launch_bounds__(256) void pack_w_kernel(const float* __restrict__ w1,
                                                     const float* __restrict__ w2,
                                                     char* __restrict__ wq,
                                                     float* __restrict__ alphah) {
  __shared__ float l1[2304], l2[2304];
  const int co = blockIdx.x;
  const int tid = threadIdx.x;
  const float* s1 = w1 + co * 2304;
  const float* s2 = w2 + co * 2304;
#pragma unroll
  for (int i = 0; i < 9; ++i) {       // stride-1 across lanes: coalesced
    l1[i * 256 + tid] = s1[i * 256 + tid];
    l2[i * 256 + tid] = s2[i * 256 + tid];
  }
  __syncthreads();
  const int ci = tid;
  float sabs = 0.f;
#pragma unroll
  for (int s = 0; s < 9; ++s) {       // LDS stride 9 (odd) -> bank-spread
    const float a = l1[ci * 9 + s];
    const float b = l2[ci * 9 + s];
    const int sa = (a > 0.f) - (a < 0.f);
    const int sb = (b > 0.f) - (b < 0.f);
    wq[(co * 9 + s) * C_ + ci] = (char)(sa + sb);   // coalesced byte store
    sabs += fabsf(a) + fabsf(b);
  }
#pragma unroll
  for (int off = 32; off > 0; off >>= 1) sabs += __shfl_down(sabs, off, 64);
  __shared__ float red[4];
  if ((tid & 63) == 0) red[tid >> 6] = sabs;
  __syncthreads();
  if (tid == 0)
    alphah[co] = (red[0] + red[1] + red[2] + red[3]) * (0.5f / 2304.0f);
}

// ---------------------------------------------------------------------------
// Pack input: sign(x) NCHW fp32 -> padded NHWC i8 [B][58][58][C].
// One block per (b, padded-y). float4 global reads, pack 4-ci bytes -> b32
// LDS writes into [x_pad][ci] tile, b128 global stores. Halo zero-filled.
// ---------------------------------------------------------------------------
#define ROWPC 272
__global__ __launch_bounds__(256) void pack_x_kernel(const float* __restrict__ in,
                                                     char* __restrict__ xp) {
  __shared__ char row[58 * ROWPC];  // 15,776 B
  const int yp = blockIdx.x % HP;
  const int b  = blockIdx.x / HP;
  const int tid = threadIdx.x;

  // zero-fill tile (covers halo + invalid-y rows)
  float4* rz = (float4*)row;
  const float4 z4 = make_float4(0.f, 0.f, 0.f, 0.f);
#pragma unroll
  for (int i = 0; i < 4; ++i) {
    const int idx = i * 256 + tid;
    if (idx < (58 * ROWPC) / 16) rz[idx] = z4;
  }
  __syncthreads();

  const int y = yp - 1;
  const int xq = tid % 14;   // x quad: x = xq*4 .. xq*4+3
  const int cs = tid / 14;   // ci-quad slot 0..18 (252..255 idle)
  if (y >= 0 && y < H_ && cs < 18) {
    const float* base = in + ((size_t)b * C_ * H_ + (size_t)y) * W_ + xq * 4;
#pragma unroll
    for (int k = 0; k < 4; ++k) {
      const int cq = cs + 18 * k;          // ci quad index 0..63
      if (cq < 64) {
        float4 f[4];
#pragma unroll
        for (int j = 0; j < 4; ++j)
          f[j] = *(const float4*)(base + (size_t)(cq * 4 + j) * (H_ * W_));
#pragma unroll
        for (int d = 0; d < 4; ++d) {
          const float v0 = (d == 0) ? f[0].x : (d == 1) ? f[0].y : (d == 2) ? f[0].z : f[0].w;
          const float v1 = (d == 0) ? f[1].x : (d == 1) ? f[1].y : (d == 2) ? f[1].z : f[1].w;
          const float v2 = (d == 0) ? f[2].x : (d == 1) ? f[2].y : (d == 2) ? f[2].z : f[2].w;
          const float v3 = (d == 0) ? f[3].x : (d == 1) ? f[3].y : (d == 2) ? f[3].z : f[3].w;
          const unsigned int pk = (unsigned)sgn8(v0) | ((unsigned)sgn8(v1) << 8) |
                                  ((unsigned)sgn8(v2) << 16) | ((unsigned)sgn8(v3) << 24);
          *(unsigned int*)&row[(xq * 4 + d + 1) * ROWPC + cq * 4] = pk;
        }
      }
    }
  }
  __syncthreads();

  // write padded row: 58 x-slots x 256 B, b128 stores
  const int cc = tid & 15;   // 16 chunks = full 256 B ci-row
  const int xo = tid >> 4;   // 16 x per iter
  char* dst = xp + (size_t)(b * HP + yp) * WPAD * C_;
#pragma unroll
  for (int it = 0; it < 4; ++it) {
    const int xs = it * 16 + xo;
    if (xs < WPAD)
      *(float4*)(dst + xs * C_ + cc * 16) = *(const float4*)&row[xs * ROWPC + cc * 16];
  }
}

// ---------------------------------------------------------------------------
// Implicit-GEMM conv, int8, BK=64 double-buffered: 36 steps (9 shifts x 4
// ci-quarters), 8KB+8KB tiles, 32 KB LDS -> 4 blocks/CU for latency hiding.
// Tile 128(co) x 128(m), 4 waves of 64x64, mfma_i32_16x16x64_i8 (1 kf/step).
// 3-bit swizzle pos=(r>>3)*32+(((r&7)<<2|(q^(r&3)))^(r&4)): each 16-lane
// frag read covers all 8 bank-quads 2-way (free). XCD-paired block decode.
// ---------------------------------------------------------------------------
__global__ __launch_bounds__(256, 4) void gemm_kernel(const char* __restrict__ xp,
                                                      const char* __restrict__ wq,
                                                      const float* __restrict__ alphah,
                                                      float* __restrict__ out) {
  __shared__ char sA[2 * 8192];  // weight tiles [buf][128 co x 64B], swizzled
  __shared__ char sB[2 * 8192];  // input tiles  [buf][128 m  x 64B], swizzled
  const int tid = threadIdx.x;

  // XCD-paired decode: blocks id, id+8 are the two co-halves of one m-tile.
  const int id = blockIdx.x;
  const int xcd = id & 7;
  const int l = id >> 3;
  const int co0 = (l & 1) * 128;
  const int m0 = ((l >> 1) * 8 + xcd) * 128;

  // Staging source decode: lane tid stages 16B to LDS pos (tid + 256*i)
  // (16B units). Invert the swizzle to find which (row r, chunk c) that is.
  const char* wsrc[2];
  const char* xsrc[2];
#pragma unroll
  for (int i = 0; i < 2; ++i) {
    const int pos = tid + 256 * i;
    const int u = pos >> 5;
    const int w = pos & 31;
    const int v2 = (w >> 4) & 1;
    const int v1 = (w >> 3) & 1;
    const int v0 = ((w >> 2) & 1) ^ v2;
    const int r = (u << 3) | (v2 << 2) | (v1 << 1) | v0;
    const int c = (w & 3) ^ ((v1 << 1) | v0);
    // A: row r = co offset; B: row r = m offset
    wsrc[i] = wq + (co0 + r) * (9 * C_) + c * 16;
    const int m = m0 + r;
    const int b = m / HW;
    const int rem = m - b * HW;
    const int y = rem / W_;
    const int x = rem - y * W_;
    xsrc[i] = xp + ((b * HP + y) * WPAD + x) * C_ + c * 16;
  }

  intx4 acc[4][4] = {};

  const int lane = tid & 63;
  const int wave = tid >> 6;
  const int wm = wave >> 1;   // co 64-half
  const int wn = wave & 1;    // m 64-half
  const int lrow = lane & 15;
  const int quad = lane >> 4;
  // read-side swizzle byte offset within each 512B (32-unit) group
  const int swzv = (((((lrow & 7) << 2) | (quad ^ (lrow & 3))) ^ (lrow & 4))) << 4;
  const int abase = (wm * 8 + (lrow >> 3)) * 512 + swzv;  // + i*1024
  const int bbase = (wn * 8 + (lrow >> 3)) * 512 + swzv;  // + j*1024

  // stage tile t (s = t>>2, kq = t&3) into buffer (t&1)
  auto stage = [&](int t) {
    const int s = t >> 2;
    const int kq = (t & 3) * 64;
    const int woff = s * C_ + kq;
    const int shoff = ((s / 3) * WPAD + (s % 3)) * C_ + kq;
    char* dA = sA + (t & 1) * 8192 + tid * 16;
    char* dB = sB + (t & 1) * 8192 + tid * 16;
#pragma unroll
    for (int i = 0; i < 2; ++i)
      __builtin_amdgcn_global_load_lds(
          (const __attribute__((address_space(1))) void*)(wsrc[i] + woff),
          (__attribute__((address_space(3))) void*)(dA + i * 4096), 16, 0, 0);
#pragma unroll
    for (int i = 0; i < 2; ++i)
      __builtin_amdgcn_global_load_lds(
          (const __attribute__((address_space(1))) void*)(xsrc[i] + shoff),
          (__attribute__((address_space(3))) void*)(dB + i * 4096), 16, 0, 0);
  };

  stage(0);
  for (int t = 0; t < 36; ++t) {
    __syncthreads();            // buf[t&1] ready; buf[(t+1)&1] reads done
    if (t < 35) stage(t + 1);   // in flight during compute(t)
    const char* bA = sA + (t & 1) * 8192;
    const char* bB = sB + (t & 1) * 8192;
    intx4 af[4], bfv[4];
#pragma unroll
    for (int i = 0; i < 4; ++i)
      af[i] = *(const intx4*)(bA + abase + i * 1024);
#pragma unroll
    for (int j = 0; j < 4; ++j)
      bfv[j] = *(const intx4*)(bB + bbase + j * 1024);
#pragma unroll
    for (int i = 0; i < 4; ++i)
#pragma unroll
      for (int j = 0; j < 4; ++j)
        acc[i][j] = __builtin_amdgcn_mfma_i32_16x16x64_i8(af[i], bfv[j],
                                                          acc[i][j], 0, 0, 0);
  }

  // Epilogue: D row (quad*4+r) = co dim, D col (lane&15) = spatial m dim.
  int ob[4];
#pragma unroll
  for (int j = 0; j < 4; ++j) {
    const int m = m0 + wn * 64 + j * 16 + lrow;
    const int b = m / HW;
    const int rem = m - b * HW;
    const int y = rem / W_;
    const int x = rem - y * W_;
    ob[j] = b * CHW + y * W_ + x;
  }
#pragma unroll
  for (int i = 0; i < 4; ++i) {
#pragma unroll
    for (int r = 0; r < 4; ++r) {
      const int co = co0 + wm * 64 + i * 16 + quad * 4 + r;
      const float sc = alphah[co];
#pragma unroll
      for (int j = 0; j < 4; ++j)
        out[ob[j] + co * HW] = (float)acc[i][j][r] * sc;
    }
  }
}

// ---------------------------------------------------------------------------
extern "C" void kernel_launch(void* const* d_in, const int* in_sizes, int n_in,
                              void* d_out, int out_size, void* d_ws, size_t ws_size,
                              hipStream_t stream) {
  const float* input = (const float*)d_in[0];
  const float* w1 = (const float*)d_in[1];
  const float* w2 = (const float*)d_in[2];
  float* out = (float*)d_out;

  char* ws = (char*)d_ws;
  char* xp = ws;                                    // 27,557,888 B
  char* wq = ws + XPAD_BYTES;                       // 589,824 B
  float* alphah = (float*)(ws + XPAD_BYTES + WPK_BYTES);  // 1,024 B

  pack_w_kernel<<<C_, 256, 0, stream>>>(w1, w2, wq, alphah);
  pack_x_kernel<<<B_ * HP, 256, 0, stream>>>(input, xp);
  gemm_kernel<<<M_TOT / 128 * (C_ / 128), 256, 0, stream>>>(xp, wq, alphah, out);
}